// Round 12
// baseline (1424.599 us; speedup 1.0000x reference)
//
#include <hip/hip_runtime.h>

// Problem constants
#define BB   2
#define HH   256
#define WW   256
#define HWSZ (HH * WW)        // 65536
#define CC   24
#define KSZ  7
#define KK   49               // 7*7
#define PADK 3
#define G    24               // channel groups (1 channel per block)
#define CPG  1
#define LSTR 24               // src halo row stride (22 padded to 24)
#define CSTR (22 * LSTR)      // channel slab in lsrc (floats)
#define LOG2E 1.44269504088896340736f

typedef __attribute__((ext_vector_type(8))) short short8;
typedef __attribute__((ext_vector_type(4))) float float4v;

// float -> bf16 bits (round-to-nearest-even) and back
__device__ __forceinline__ short f2bf(float x) {
  unsigned u = __builtin_bit_cast(unsigned, x);
  unsigned r = u + 0x7FFFu + ((u >> 16) & 1u);
  return (short)(r >> 16);
}
__device__ __forceinline__ float bf2f(short h) {
  unsigned u = ((unsigned)(unsigned short)h) << 16;
  return __builtin_bit_cast(float, u);
}

// ---------------------------------------------------------------------------
// Merged setup (one dispatch):
// blocks 0..191: split-bf16 W fragments in FRAG-MAJOR (consumer-lane) order,
//   pre-scaled by log2e. wsW[blk][lane*8+j] = W[m=lane&15][k=(lane>>4)*8+j],
//   blk = (cg*4+mt)*2+s, cg = global channel 0..23.
// blocks 192..703: split-bf16 B fragments (texture patch matrix), identical
//   for all 4 diffusion dispatches.
// blocks 704..1215: init out = b_td (FINAL accumulates atomically) and
//   zsum = 0 (FIRST accumulates z atomically; ws is poisoned every launch).
// ---------------------------------------------------------------------------
__global__ __launch_bounds__(256) void k_setup(
    const float* __restrict__ w_kp, const float* __restrict__ b_kp,
    const float* __restrict__ tex, short* __restrict__ wsW,
    short* __restrict__ wsB, const float* __restrict__ b_td,
    float* __restrict__ outp, float* __restrict__ zsum) {
  __shared__ float lt[3 * 324];   // 18x18 tex halo
  __shared__ int lltk[32];        // k -> tex-halo offset
  int blk = blockIdx.x;
  if (blk < 192) {
    int s = blk & 1, mt = (blk >> 1) & 3, cg = blk >> 3;
    for (int idx = threadIdx.x; idx < 512; idx += 256) {
      int l = idx >> 3, j = idx & 7;          // consumer lane, reg element
      int kk = mt * 16 + (l & 15);            // tap row (A row m)
      int k = (l >> 4) * 8 + j;               // K index (q*8+j)
      float v = 0.f;
      if (kk < KK && k < 28)
        v = ((k < 27) ? w_kp[((size_t)cg * KK + kk) * 27 + k]
                      : b_kp[cg * KK + kk]) * LOG2E;
      short hi = f2bf(v);
      short h = (s == 0) ? hi : f2bf(v - bf2f(hi));
      wsW[(size_t)blk * 512 + idx] = h;
    }
    return;
  }
  if (blk >= 704) {
    int i = (blk - 704) * 256 + threadIdx.x;   // 0 .. 131071 = BB*HWSZ
    outp[i] = b_td[0];
    zsum[i] = 0.f;
    return;
  }
  int tb = blk - 192;                     // 0..511
  int b = tb >> 8, tile = tb & 255;
  int y0 = (tile >> 4) * 16, x0 = (tile & 15) * 16;
  int tid = threadIdx.x, lane = tid & 63, wv = tid >> 6;
  int q = lane >> 4, col = lane & 15;

  if (tid < 32) {
    int k = tid, v;
    if (k < 27) v = (k / 9) * 324 + ((k % 9) / 3) * 18 + (k % 3);
    else if (k == 27) v = -1;     // bias slot: patch value 1.0
    else v = -2;                  // K padding: 0.0
    lltk[k] = v;
  }
  for (int idx = tid; idx < 972; idx += 256) {
    int ci = idx / 324, r = idx % 324;
    int iy = r / 18, ix = r % 18;
    int yy = y0 + iy - 1, xx = x0 + ix - 1;
    bool ok = (yy >= 0 && yy < HH && xx >= 0 && xx < WW);
    lt[idx] = ok ? tex[((size_t)b * 3 + ci) * HWSZ + yy * WW + xx] : 0.f;
  }
  __syncthreads();

  int tko[8];
#pragma unroll
  for (int j = 0; j < 8; ++j) tko[j] = lltk[q * 8 + j];
  int4* w4 = (int4*)wsB;
#pragma unroll
  for (int nt = 0; nt < 4; ++nt) {
    short8 hi, lo;
#pragma unroll
    for (int j = 0; j < 8; ++j) {
      int o = tko[j];
      float v = (o == -1) ? 1.f
                          : ((o == -2) ? 0.f : lt[o + (wv * 4 + nt) * 18 + col]);
      short h = f2bf(v);
      hi[j] = h;
      lo[j] = f2bf(v - bf2f(h));
    }
    size_t base = ((((size_t)(b * 256 + tile) * 4 + wv) * 4 + nt) * 2);
    w4[(base + 0) * 64 + lane] = __builtin_bit_cast(int4, hi);
    w4[(base + 1) * 64 + lane] = __builtin_bit_cast(int4, lo);
  }
}

// ---------------------------------------------------------------------------
// One diffusion iteration, split-bf16 MFMA logit conv, exp2 epilogue.
// R12: ONE channel per block (G=24) -> LDS footprint 12.7 KB -> 8 blocks/CU
// = 32 waves/CU (hw max) for pipe overlap; aggregate work invariant.
// Inner loop = R10-proven: np outer (2 passes x 2 pixel rows, 2 C-chains),
// mt unrolled with PRECOMPUTED offs[16] (const-indexed), frag-major LDS A
// reads (conflict-free b128). z atomically accumulated by FIRST into zsum;
// FINAL atomically accumulates to out (pre-init b_td by k_setup).
// ---------------------------------------------------------------------------
template <bool FIRST, bool FINAL>
__global__ __launch_bounds__(256, 8) void k_diffuse_m(
    const float* __restrict__ depth, const float* __restrict__ src,
    const float* __restrict__ zsum, const float* __restrict__ w_dp,
    const float* __restrict__ b_dp, const short* __restrict__ wsW,
    const short* __restrict__ wsB, float* __restrict__ dst,
    const float* __restrict__ w_td, float* __restrict__ outp) {
  __shared__ __align__(16) short lw[8 * 512];    // 8192 B (4 mt x 2 s frags)
  __shared__ float lsrc[CSTR];                   // 2112 B (1 ch halo)
  __shared__ float ldp[FIRST ? 576 : 4];         // depth halo (FIRST only)

  int b = blockIdx.z / G, g = blockIdx.z % G;    // g = channel
  int x0 = blockIdx.x * 16, y0 = blockIdx.y * 16;
  int tile = blockIdx.y * 16 + blockIdx.x;
  int tid = threadIdx.x, lane = tid & 63, wv = tid >> 6;
  int q = lane >> 4, col = lane & 15;

  // ---- phase A: W->LDS copy (8 KB, layout-preserving), depth halo ----
  {
    const int4* s4 = (const int4*)(wsW + (size_t)g * 4096);
    int4* d4 = (int4*)lw;
    d4[tid] = s4[tid];
    d4[tid + 256] = s4[tid + 256];
  }
  if (FIRST) {
    for (int idx = tid; idx < 576; idx += 256) {  // depth halo 24x24 @(-4,-4)
      int iy = idx / 24, ix = idx % 24;
      int yy = y0 + iy - 4, xx = x0 + ix - 4;
      bool ok = (yy >= 0 && yy < HH && xx >= 0 && xx < WW);
      ldp[idx] = ok ? depth[(size_t)b * HWSZ + yy * WW + xx] : 0.f;
    }
  }
  __syncthreads();

  // ---- phase B: src halo staging (22x22 @(-3,-3)), single channel ----
  for (int idx = tid; idx < 484; idx += 256) {
    int iy = idx / 22, ix = idx % 22;
    int yy = y0 + iy - PADK, xx = x0 + ix - PADK;
    bool ok = (yy >= 0 && yy < HH && xx >= 0 && xx < WW);
    if (FIRST) {
      float a = b_dp[g];
#pragma unroll
      for (int dy = 0; dy < 3; ++dy)
#pragma unroll
        for (int dx = 0; dx < 3; ++dx)
          a = fmaf(w_dp[g * 9 + dy * 3 + dx], ldp[(iy + dy) * 24 + (ix + dx)], a);
      lsrc[iy * LSTR + ix] = ok ? a : 0.f;
    } else {
      float sc = 0.f;
      if (ok) sc = 1.f / zsum[b * HWSZ + yy * WW + xx];
      lsrc[iy * LSTR + ix] =
          ok ? src[((size_t)b * CC + g) * HWSZ + yy * WW + xx] * sc : 0.f;
    }
  }
  __syncthreads();

  // ---- per-lane tap offsets in registers (j = mt*4+i, constant-indexed):
  // t = mt*16 + q*4 + i; off = t + 17*(t/7) - 75, t/7 == (t*37)>>8 (t<=62).
  // Pad taps (t>48) clamp to 48; their e is forced 0 in the mt==3 path.
  int offs[16];
#pragma unroll
  for (int j = 0; j < 16; ++j) {
    int t = (j >> 2) * 16 + q * 4 + (j & 3);
    t = (t < 48) ? t : 48;
    offs[j] = t + 17 * ((t * 37) >> 8) - 75;
  }

  const short* lA = lw + lane * 8;
  const int4* wB = (const int4*)wsB + ((size_t)(b * 256 + tile) * 4 + wv) * 512;

#pragma unroll 1
  for (int np = 0; np < 2; ++np) {
    // B fragments for this pass's 2 pixel rows (precomputed, coalesced b128)
    short8 Bh0 = __builtin_bit_cast(short8, wB[(np * 4 + 0) * 64 + lane]);
    short8 Bl0 = __builtin_bit_cast(short8, wB[(np * 4 + 1) * 64 + lane]);
    short8 Bh1 = __builtin_bit_cast(short8, wB[(np * 4 + 2) * 64 + lane]);
    short8 Bl1 = __builtin_bit_cast(short8, wB[(np * 4 + 3) * 64 + lane]);
    const float* base = lsrc + (wv * 4 + np * 2 + 3) * LSTR + col + 3;
    float zacc[2] = {0.f, 0.f};
    float accc[2] = {0.f, 0.f};

#pragma unroll
    for (int mt = 0; mt < 4; ++mt) {
      short8 Ah = *(const short8*)(lA + mt * 1024);
      short8 Al = *(const short8*)(lA + mt * 1024 + 512);

      float4v C0 = {0.f, 0.f, 0.f, 0.f}, C1 = {0.f, 0.f, 0.f, 0.f};
      C0 = __builtin_amdgcn_mfma_f32_16x16x32_bf16(Ah, Bh0, C0, 0, 0, 0);
      C1 = __builtin_amdgcn_mfma_f32_16x16x32_bf16(Ah, Bh1, C1, 0, 0, 0);
      C0 = __builtin_amdgcn_mfma_f32_16x16x32_bf16(Ah, Bl0, C0, 0, 0, 0);
      C1 = __builtin_amdgcn_mfma_f32_16x16x32_bf16(Ah, Bl1, C1, 0, 0, 0);
      C0 = __builtin_amdgcn_mfma_f32_16x16x32_bf16(Al, Bh0, C0, 0, 0, 0);
      C1 = __builtin_amdgcn_mfma_f32_16x16x32_bf16(Al, Bh1, C1, 0, 0, 0);

      if (mt < 3) {
        const float* t0 = base + offs[mt * 4 + 0];
        const float* t1 = base + offs[mt * 4 + 1];
        const float* t2 = base + offs[mt * 4 + 2];
        const float* t3 = base + offs[mt * 4 + 3];
        float e00 = __builtin_amdgcn_exp2f(C0[0]);
        float e01 = __builtin_amdgcn_exp2f(C0[1]);
        float e02 = __builtin_amdgcn_exp2f(C0[2]);
        float e03 = __builtin_amdgcn_exp2f(C0[3]);
        float e10 = __builtin_amdgcn_exp2f(C1[0]);
        float e11 = __builtin_amdgcn_exp2f(C1[1]);
        float e12 = __builtin_amdgcn_exp2f(C1[2]);
        float e13 = __builtin_amdgcn_exp2f(C1[3]);
        if (FIRST) {
          zacc[0] += (e00 + e01) + (e02 + e03);
          zacc[1] += (e10 + e11) + (e12 + e13);
        }
        float a0 = accc[0], a1 = accc[1];
        a0 = fmaf(e00, t0[0], a0); a1 = fmaf(e10, t0[LSTR], a1);
        a0 = fmaf(e01, t1[0], a0); a1 = fmaf(e11, t1[LSTR], a1);
        a0 = fmaf(e02, t2[0], a0); a1 = fmaf(e12, t2[LSTR], a1);
        a0 = fmaf(e03, t3[0], a0); a1 = fmaf(e13, t3[LSTR], a1);
        accc[0] = a0; accc[1] = a1;
      } else {
        // only tap row 48 (q==0, reg 0) is real in M-tile 3
        const float* t0 = base + offs[12];
        float e0 = (q == 0) ? __builtin_amdgcn_exp2f(C0[0]) : 0.f;
        float e1 = (q == 0) ? __builtin_amdgcn_exp2f(C1[0]) : 0.f;
        if (FIRST) { zacc[0] += e0; zacc[1] += e1; }
        accc[0] = fmaf(e0, t0[0], accc[0]);
        accc[1] = fmaf(e1, t0[LSTR], accc[1]);
      }
    }

    // pass complete: reduce across quads, emit
#pragma unroll
    for (int t = 0; t < 2; ++t) {
      float v = accc[t];
      v += __shfl_xor(v, 16, 64);
      v += __shfl_xor(v, 32, 64);
      int p = (y0 + wv * 4 + np * 2 + t) * WW + (x0 + col);
      if (FINAL) {
        if (lane < 16) {
          float rz = 1.f / zsum[b * HWSZ + p];
          atomicAdd(&outp[(size_t)b * HWSZ + p], w_td[g] * v * rz);
        }
      } else {
        if (lane < 16) dst[((size_t)b * CC + g) * HWSZ + p] = v;
      }
      if (FIRST) {
        float z = zacc[t];
        z += __shfl_xor(z, 16, 64);
        z += __shfl_xor(z, 32, 64);
        if (lane < 16) atomicAdd((float*)&zsum[b * HWSZ + p], z);
      }
    }
  }
}

// ---------------------------------------------------------------------------
extern "C" void kernel_launch(void* const* d_in, const int* in_sizes, int n_in,
                              void* d_out, int out_size, void* d_ws, size_t ws_size,
                              hipStream_t stream) {
  const float* depth = (const float*)d_in[0];
  const float* tex   = (const float*)d_in[1];
  const float* w_dp  = (const float*)d_in[2];
  const float* b_dp  = (const float*)d_in[3];
  const float* w_kp  = (const float*)d_in[4];
  const float* b_kp  = (const float*)d_in[5];
  const float* w_td  = (const float*)d_in[6];
  const float* b_td  = (const float*)d_in[7];
  float* out = (float*)d_out;

  // ws: bufA/bufB (12.58 MB ea) + zsum (0.5 MB) + wsW (0.2 MB) + wsB (16.8 MB)
  char* ws = (char*)d_ws;
  const size_t buf_b = (size_t)BB * CC * HWSZ * 4;
  float* bufA = (float*)ws;
  float* bufB = (float*)(ws + buf_b);
  float* zsum = (float*)(ws + 2 * buf_b);
  short* wsW  = (short*)(ws + 2 * buf_b + (size_t)BB * HWSZ * 4);
  short* wsB  = (short*)(ws + 2 * buf_b + (size_t)BB * HWSZ * 4 + 192 * 512 * 2);

  k_setup<<<dim3(192 + 512 + 512), dim3(256), 0, stream>>>(
      w_kp, b_kp, tex, wsW, wsB, b_td, out, zsum);

  dim3 grid(WW / 16, HH / 16, BB * G), blk(256);

  // iter1: fused depth_latent; emits unnormalized acc + atomic z into zsum
  k_diffuse_m<true, false><<<grid, blk, 0, stream>>>(
      depth, nullptr, zsum, w_dp, b_dp, wsW, wsB, bufB, w_td, nullptr);
  // iters 2,3: unnormalized ping-pong, 1/zsum folded into staging
  k_diffuse_m<false, false><<<grid, blk, 0, stream>>>(
      depth, bufB, zsum, w_dp, b_dp, wsW, wsB, bufA, w_td, nullptr);
  k_diffuse_m<false, false><<<grid, blk, 0, stream>>>(
      depth, bufA, zsum, w_dp, b_dp, wsW, wsB, bufB, w_td, nullptr);
  // iter4: fused to_depth, atomic accumulate into out (pre-init by k_setup)
  k_diffuse_m<false, true><<<grid, blk, 0, stream>>>(
      depth, bufB, zsum, w_dp, b_dp, wsW, wsB, nullptr, w_td, out);
}

// Round 13
// 1040.301 us; speedup vs baseline: 1.3694x; 1.3694x over previous
//
#include <hip/hip_runtime.h>

// Problem constants
#define BB   2
#define HH   256
#define WW   256
#define HWSZ (HH * WW)        // 65536
#define CC   24
#define KSZ  7
#define KK   49               // 7*7
#define PADK 3
#define G    24               // channel groups (1 channel per block)
#define CPG  1
#define LSTR 24               // src halo row stride (22 padded to 24)
#define CSTR (22 * LSTR)      // channel slab in lsrc (floats)
#define LOG2E 1.44269504088896340736f

typedef __attribute__((ext_vector_type(8))) short short8;
typedef __attribute__((ext_vector_type(4))) float float4v;

// float -> bf16 bits (round-to-nearest-even) and back
__device__ __forceinline__ short f2bf(float x) {
  unsigned u = __builtin_bit_cast(unsigned, x);
  unsigned r = u + 0x7FFFu + ((u >> 16) & 1u);
  return (short)(r >> 16);
}
__device__ __forceinline__ float bf2f(short h) {
  unsigned u = ((unsigned)(unsigned short)h) << 16;
  return __builtin_bit_cast(float, u);
}

// ---------------------------------------------------------------------------
// Merged setup (one dispatch):
// blocks 0..191: split-bf16 W fragments in FRAG-MAJOR (consumer-lane) order,
//   pre-scaled by log2e. wsW[blk][lane*8+j] = W[m=lane&15][k=(lane>>4)*8+j],
//   blk = (cg*4+mt)*2+s, cg = global channel 0..23.
// blocks 192..703: split-bf16 B fragments (texture patch matrix), identical
//   for all 4 diffusion dispatches.
// blocks 704..1215: init out = b_td (FINAL accumulates atomically) and
//   zsum = 0 (FIRST accumulates z atomically; ws is poisoned every launch).
// ---------------------------------------------------------------------------
__global__ __launch_bounds__(256) void k_setup(
    const float* __restrict__ w_kp, const float* __restrict__ b_kp,
    const float* __restrict__ tex, short* __restrict__ wsW,
    short* __restrict__ wsB, const float* __restrict__ b_td,
    float* __restrict__ outp, float* __restrict__ zsum) {
  __shared__ float lt[3 * 324];   // 18x18 tex halo
  __shared__ int lltk[32];        // k -> tex-halo offset
  int blk = blockIdx.x;
  if (blk < 192) {
    int s = blk & 1, mt = (blk >> 1) & 3, cg = blk >> 3;
    for (int idx = threadIdx.x; idx < 512; idx += 256) {
      int l = idx >> 3, j = idx & 7;          // consumer lane, reg element
      int kk = mt * 16 + (l & 15);            // tap row (A row m)
      int k = (l >> 4) * 8 + j;               // K index (q*8+j)
      float v = 0.f;
      if (kk < KK && k < 28)
        v = ((k < 27) ? w_kp[((size_t)cg * KK + kk) * 27 + k]
                      : b_kp[cg * KK + kk]) * LOG2E;
      short hi = f2bf(v);
      short h = (s == 0) ? hi : f2bf(v - bf2f(hi));
      wsW[(size_t)blk * 512 + idx] = h;
    }
    return;
  }
  if (blk >= 704) {
    int i = (blk - 704) * 256 + threadIdx.x;   // 0 .. 131071 = BB*HWSZ
    outp[i] = b_td[0];
    zsum[i] = 0.f;
    return;
  }
  int tb = blk - 192;                     // 0..511
  int b = tb >> 8, tile = tb & 255;
  int y0 = (tile >> 4) * 16, x0 = (tile & 15) * 16;
  int tid = threadIdx.x, lane = tid & 63, wv = tid >> 6;
  int q = lane >> 4, col = lane & 15;

  if (tid < 32) {
    int k = tid, v;
    if (k < 27) v = (k / 9) * 324 + ((k % 9) / 3) * 18 + (k % 3);
    else if (k == 27) v = -1;     // bias slot: patch value 1.0
    else v = -2;                  // K padding: 0.0
    lltk[k] = v;
  }
  for (int idx = tid; idx < 972; idx += 256) {
    int ci = idx / 324, r = idx % 324;
    int iy = r / 18, ix = r % 18;
    int yy = y0 + iy - 1, xx = x0 + ix - 1;
    bool ok = (yy >= 0 && yy < HH && xx >= 0 && xx < WW);
    lt[idx] = ok ? tex[((size_t)b * 3 + ci) * HWSZ + yy * WW + xx] : 0.f;
  }
  __syncthreads();

  int tko[8];
#pragma unroll
  for (int j = 0; j < 8; ++j) tko[j] = lltk[q * 8 + j];
  int4* w4 = (int4*)wsB;
#pragma unroll
  for (int nt = 0; nt < 4; ++nt) {
    short8 hi, lo;
#pragma unroll
    for (int j = 0; j < 8; ++j) {
      int o = tko[j];
      float v = (o == -1) ? 1.f
                          : ((o == -2) ? 0.f : lt[o + (wv * 4 + nt) * 18 + col]);
      short h = f2bf(v);
      hi[j] = h;
      lo[j] = f2bf(v - bf2f(h));
    }
    size_t base = ((((size_t)(b * 256 + tile) * 4 + wv) * 4 + nt) * 2);
    w4[(base + 0) * 64 + lane] = __builtin_bit_cast(int4, hi);
    w4[(base + 1) * 64 + lane] = __builtin_bit_cast(int4, lo);
  }
}

// ---------------------------------------------------------------------------
// One diffusion iteration, split-bf16 MFMA logit conv, exp2 epilogue.
// R13 = R12 structure (ONE channel per block, 12.7 KB LDS) with the spill
// fixed: __launch_bounds__(256,6) -> 84-VGPR cap, comfortably above the
// ~64 the R10-proven inner loop needs (R12's (256,8)=64 cap spilled).
// Residency ~6 blocks/CU = 24 waves/CU (vs R10's 11) for pipe overlap.
// Inner loop identical to R10: np outer (2 passes x 2 pixel rows, 2
// C-chains), mt unrolled with PRECOMPUTED offs[16], frag-major LDS A reads
// (conflict-free b128). z atomically accumulated by FIRST into zsum;
// FINAL atomically accumulates to out (pre-init b_td by k_setup).
// ---------------------------------------------------------------------------
template <bool FIRST, bool FINAL>
__global__ __launch_bounds__(256, 6) void k_diffuse_m(
    const float* __restrict__ depth, const float* __restrict__ src,
    const float* __restrict__ zsum, const float* __restrict__ w_dp,
    const float* __restrict__ b_dp, const short* __restrict__ wsW,
    const short* __restrict__ wsB, float* __restrict__ dst,
    const float* __restrict__ w_td, float* __restrict__ outp) {
  __shared__ __align__(16) short lw[8 * 512];    // 8192 B (4 mt x 2 s frags)
  __shared__ float lsrc[CSTR];                   // 2112 B (1 ch halo)
  __shared__ float ldp[FIRST ? 576 : 4];         // depth halo (FIRST only)

  int b = blockIdx.z / G, g = blockIdx.z % G;    // g = channel
  int x0 = blockIdx.x * 16, y0 = blockIdx.y * 16;
  int tile = blockIdx.y * 16 + blockIdx.x;
  int tid = threadIdx.x, lane = tid & 63, wv = tid >> 6;
  int q = lane >> 4, col = lane & 15;

  // ---- phase A: W->LDS copy (8 KB, layout-preserving), depth halo ----
  {
    const int4* s4 = (const int4*)(wsW + (size_t)g * 4096);
    int4* d4 = (int4*)lw;
    d4[tid] = s4[tid];
    d4[tid + 256] = s4[tid + 256];
  }
  if (FIRST) {
    for (int idx = tid; idx < 576; idx += 256) {  // depth halo 24x24 @(-4,-4)
      int iy = idx / 24, ix = idx % 24;
      int yy = y0 + iy - 4, xx = x0 + ix - 4;
      bool ok = (yy >= 0 && yy < HH && xx >= 0 && xx < WW);
      ldp[idx] = ok ? depth[(size_t)b * HWSZ + yy * WW + xx] : 0.f;
    }
  }
  __syncthreads();

  // ---- phase B: src halo staging (22x22 @(-3,-3)), single channel ----
  for (int idx = tid; idx < 484; idx += 256) {
    int iy = idx / 22, ix = idx % 22;
    int yy = y0 + iy - PADK, xx = x0 + ix - PADK;
    bool ok = (yy >= 0 && yy < HH && xx >= 0 && xx < WW);
    if (FIRST) {
      float a = b_dp[g];
#pragma unroll
      for (int dy = 0; dy < 3; ++dy)
#pragma unroll
        for (int dx = 0; dx < 3; ++dx)
          a = fmaf(w_dp[g * 9 + dy * 3 + dx], ldp[(iy + dy) * 24 + (ix + dx)], a);
      lsrc[iy * LSTR + ix] = ok ? a : 0.f;
    } else {
      float sc = 0.f;
      if (ok) sc = 1.f / zsum[b * HWSZ + yy * WW + xx];
      lsrc[iy * LSTR + ix] =
          ok ? src[((size_t)b * CC + g) * HWSZ + yy * WW + xx] * sc : 0.f;
    }
  }
  __syncthreads();

  // ---- per-lane tap offsets in registers (j = mt*4+i, constant-indexed):
  // t = mt*16 + q*4 + i; off = t + 17*(t/7) - 75, t/7 == (t*37)>>8 (t<=62).
  // Pad taps (t>48) clamp to 48; their e is forced 0 in the mt==3 path.
  int offs[16];
#pragma unroll
  for (int j = 0; j < 16; ++j) {
    int t = (j >> 2) * 16 + q * 4 + (j & 3);
    t = (t < 48) ? t : 48;
    offs[j] = t + 17 * ((t * 37) >> 8) - 75;
  }

  const short* lA = lw + lane * 8;
  const int4* wB = (const int4*)wsB + ((size_t)(b * 256 + tile) * 4 + wv) * 512;

#pragma unroll 1
  for (int np = 0; np < 2; ++np) {
    // B fragments for this pass's 2 pixel rows (precomputed, coalesced b128)
    short8 Bh0 = __builtin_bit_cast(short8, wB[(np * 4 + 0) * 64 + lane]);
    short8 Bl0 = __builtin_bit_cast(short8, wB[(np * 4 + 1) * 64 + lane]);
    short8 Bh1 = __builtin_bit_cast(short8, wB[(np * 4 + 2) * 64 + lane]);
    short8 Bl1 = __builtin_bit_cast(short8, wB[(np * 4 + 3) * 64 + lane]);
    const float* base = lsrc + (wv * 4 + np * 2 + 3) * LSTR + col + 3;
    float zacc[2] = {0.f, 0.f};
    float accc[2] = {0.f, 0.f};

#pragma unroll
    for (int mt = 0; mt < 4; ++mt) {
      short8 Ah = *(const short8*)(lA + mt * 1024);
      short8 Al = *(const short8*)(lA + mt * 1024 + 512);

      float4v C0 = {0.f, 0.f, 0.f, 0.f}, C1 = {0.f, 0.f, 0.f, 0.f};
      C0 = __builtin_amdgcn_mfma_f32_16x16x32_bf16(Ah, Bh0, C0, 0, 0, 0);
      C1 = __builtin_amdgcn_mfma_f32_16x16x32_bf16(Ah, Bh1, C1, 0, 0, 0);
      C0 = __builtin_amdgcn_mfma_f32_16x16x32_bf16(Ah, Bl0, C0, 0, 0, 0);
      C1 = __builtin_amdgcn_mfma_f32_16x16x32_bf16(Ah, Bl1, C1, 0, 0, 0);
      C0 = __builtin_amdgcn_mfma_f32_16x16x32_bf16(Al, Bh0, C0, 0, 0, 0);
      C1 = __builtin_amdgcn_mfma_f32_16x16x32_bf16(Al, Bh1, C1, 0, 0, 0);

      if (mt < 3) {
        const float* t0 = base + offs[mt * 4 + 0];
        const float* t1 = base + offs[mt * 4 + 1];
        const float* t2 = base + offs[mt * 4 + 2];
        const float* t3 = base + offs[mt * 4 + 3];
        float e00 = __builtin_amdgcn_exp2f(C0[0]);
        float e01 = __builtin_amdgcn_exp2f(C0[1]);
        float e02 = __builtin_amdgcn_exp2f(C0[2]);
        float e03 = __builtin_amdgcn_exp2f(C0[3]);
        float e10 = __builtin_amdgcn_exp2f(C1[0]);
        float e11 = __builtin_amdgcn_exp2f(C1[1]);
        float e12 = __builtin_amdgcn_exp2f(C1[2]);
        float e13 = __builtin_amdgcn_exp2f(C1[3]);
        if (FIRST) {
          zacc[0] += (e00 + e01) + (e02 + e03);
          zacc[1] += (e10 + e11) + (e12 + e13);
        }
        float a0 = accc[0], a1 = accc[1];
        a0 = fmaf(e00, t0[0], a0); a1 = fmaf(e10, t0[LSTR], a1);
        a0 = fmaf(e01, t1[0], a0); a1 = fmaf(e11, t1[LSTR], a1);
        a0 = fmaf(e02, t2[0], a0); a1 = fmaf(e12, t2[LSTR], a1);
        a0 = fmaf(e03, t3[0], a0); a1 = fmaf(e13, t3[LSTR], a1);
        accc[0] = a0; accc[1] = a1;
      } else {
        // only tap row 48 (q==0, reg 0) is real in M-tile 3
        const float* t0 = base + offs[12];
        float e0 = (q == 0) ? __builtin_amdgcn_exp2f(C0[0]) : 0.f;
        float e1 = (q == 0) ? __builtin_amdgcn_exp2f(C1[0]) : 0.f;
        if (FIRST) { zacc[0] += e0; zacc[1] += e1; }
        accc[0] = fmaf(e0, t0[0], accc[0]);
        accc[1] = fmaf(e1, t0[LSTR], accc[1]);
      }
    }

    // pass complete: reduce across quads, emit
#pragma unroll
    for (int t = 0; t < 2; ++t) {
      float v = accc[t];
      v += __shfl_xor(v, 16, 64);
      v += __shfl_xor(v, 32, 64);
      int p = (y0 + wv * 4 + np * 2 + t) * WW + (x0 + col);
      if (FINAL) {
        if (lane < 16) {
          float rz = 1.f / zsum[b * HWSZ + p];
          atomicAdd(&outp[(size_t)b * HWSZ + p], w_td[g] * v * rz);
        }
      } else {
        if (lane < 16) dst[((size_t)b * CC + g) * HWSZ + p] = v;
      }
      if (FIRST) {
        float z = zacc[t];
        z += __shfl_xor(z, 16, 64);
        z += __shfl_xor(z, 32, 64);
        if (lane < 16) atomicAdd((float*)&zsum[b * HWSZ + p], z);
      }
    }
  }
}

// ---------------------------------------------------------------------------
extern "C" void kernel_launch(void* const* d_in, const int* in_sizes, int n_in,
                              void* d_out, int out_size, void* d_ws, size_t ws_size,
                              hipStream_t stream) {
  const float* depth = (const float*)d_in[0];
  const float* tex   = (const float*)d_in[1];
  const float* w_dp  = (const float*)d_in[2];
  const float* b_dp  = (const float*)d_in[3];
  const float* w_kp  = (const float*)d_in[4];
  const float* b_kp  = (const float*)d_in[5];
  const float* w_td  = (const float*)d_in[6];
  const float* b_td  = (const float*)d_in[7];
  float* out = (float*)d_out;

  // ws: bufA/bufB (12.58 MB ea) + zsum (0.5 MB) + wsW (0.2 MB) + wsB (16.8 MB)
  char* ws = (char*)d_ws;
  const size_t buf_b = (size_t)BB * CC * HWSZ * 4;
  float* bufA = (float*)ws;
  float* bufB = (float*)(ws + buf_b);
  float* zsum = (float*)(ws + 2 * buf_b);
  short* wsW  = (short*)(ws + 2 * buf_b + (size_t)BB * HWSZ * 4);
  short* wsB  = (short*)(ws + 2 * buf_b + (size_t)BB * HWSZ * 4 + 192 * 512 * 2);

  k_setup<<<dim3(192 + 512 + 512), dim3(256), 0, stream>>>(
      w_kp, b_kp, tex, wsW, wsB, b_td, out, zsum);

  dim3 grid(WW / 16, HH / 16, BB * G), blk(256);

  // iter1: fused depth_latent; emits unnormalized acc + atomic z into zsum
  k_diffuse_m<true, false><<<grid, blk, 0, stream>>>(
      depth, nullptr, zsum, w_dp, b_dp, wsW, wsB, bufB, w_td, nullptr);
  // iters 2,3: unnormalized ping-pong, 1/zsum folded into staging
  k_diffuse_m<false, false><<<grid, blk, 0, stream>>>(
      depth, bufB, zsum, w_dp, b_dp, wsW, wsB, bufA, w_td, nullptr);
  k_diffuse_m<false, false><<<grid, blk, 0, stream>>>(
      depth, bufA, zsum, w_dp, b_dp, wsW, wsB, bufB, w_td, nullptr);
  // iter4: fused to_depth, atomic accumulate into out (pre-init by k_setup)
  k_diffuse_m<false, true><<<grid, blk, 0, stream>>>(
      depth, bufB, zsum, w_dp, b_dp, wsW, wsB, nullptr, w_td, out);
}

// Round 14
// 387.205 us; speedup vs baseline: 3.6792x; 2.6867x over previous
//
#include <hip/hip_runtime.h>

// Problem constants
#define BB   2
#define HH   256
#define WW   256
#define HWSZ (HH * WW)        // 65536
#define CC   24
#define KSZ  7
#define KK   49               // 7*7
#define PADK 3
#define G    24               // one channel per block
#define LSTR 24               // src halo row stride (22 padded to 24)
#define CSTR (22 * LSTR)      // halo slab (floats)
#define LOG2E 1.44269504088896340736f

typedef __attribute__((ext_vector_type(8))) short short8;
typedef __attribute__((ext_vector_type(4))) float float4v;

// float -> bf16 bits (round-to-nearest-even) and back
__device__ __forceinline__ short f2bf(float x) {
  unsigned u = __builtin_bit_cast(unsigned, x);
  unsigned r = u + 0x7FFFu + ((u >> 16) & 1u);
  return (short)(r >> 16);
}
__device__ __forceinline__ float bf2f(short h) {
  unsigned u = ((unsigned)(unsigned short)h) << 16;
  return __builtin_bit_cast(float, u);
}

// ---------------------------------------------------------------------------
// Merged setup (one dispatch):
// blocks 0..191: split-bf16 W fragments in FRAG-MAJOR (consumer-lane) order,
//   pre-scaled by log2e. wsW[blk][lane*8+j] = W[m=lane&15][k=(lane>>4)*8+j],
//   blk = (cg*4+mt)*2+s, cg = channel 0..23. Consumed straight from L2.
// blocks 192..703: split-bf16 B fragments (texture patch matrix), identical
//   for all 4 diffusion dispatches.
// blocks 704..1215: init out = b_td and zsum = 0 (ws re-poisoned per launch).
// ---------------------------------------------------------------------------
__global__ __launch_bounds__(256) void k_setup(
    const float* __restrict__ w_kp, const float* __restrict__ b_kp,
    const float* __restrict__ tex, short* __restrict__ wsW,
    short* __restrict__ wsB, const float* __restrict__ b_td,
    float* __restrict__ outp, float* __restrict__ zsum) {
  __shared__ float lt[3 * 324];   // 18x18 tex halo
  __shared__ int lltk[32];        // k -> tex-halo offset
  int blk = blockIdx.x;
  if (blk < 192) {
    int s = blk & 1, mt = (blk >> 1) & 3, cg = blk >> 3;
    for (int idx = threadIdx.x; idx < 512; idx += 256) {
      int l = idx >> 3, j = idx & 7;          // consumer lane, reg element
      int kk = mt * 16 + (l & 15);            // tap row (A row m)
      int k = (l >> 4) * 8 + j;               // K index (q*8+j)
      float v = 0.f;
      if (kk < KK && k < 28)
        v = ((k < 27) ? w_kp[((size_t)cg * KK + kk) * 27 + k]
                      : b_kp[cg * KK + kk]) * LOG2E;
      short hi = f2bf(v);
      short h = (s == 0) ? hi : f2bf(v - bf2f(hi));
      wsW[(size_t)blk * 512 + idx] = h;
    }
    return;
  }
  if (blk >= 704) {
    int i = (blk - 704) * 256 + threadIdx.x;   // 0 .. 131071 = BB*HWSZ
    outp[i] = b_td[0];
    zsum[i] = 0.f;
    return;
  }
  int tb = blk - 192;                     // 0..511
  int b = tb >> 8, tile = tb & 255;
  int y0 = (tile >> 4) * 16, x0 = (tile & 15) * 16;
  int tid = threadIdx.x, lane = tid & 63, wv = tid >> 6;
  int q = lane >> 4, col = lane & 15;

  if (tid < 32) {
    int k = tid, v;
    if (k < 27) v = (k / 9) * 324 + ((k % 9) / 3) * 18 + (k % 3);
    else if (k == 27) v = -1;     // bias slot: patch value 1.0
    else v = -2;                  // K padding: 0.0
    lltk[k] = v;
  }
  for (int idx = tid; idx < 972; idx += 256) {
    int ci = idx / 324, r = idx % 324;
    int iy = r / 18, ix = r % 18;
    int yy = y0 + iy - 1, xx = x0 + ix - 1;
    bool ok = (yy >= 0 && yy < HH && xx >= 0 && xx < WW);
    lt[idx] = ok ? tex[((size_t)b * 3 + ci) * HWSZ + yy * WW + xx] : 0.f;
  }
  __syncthreads();

  int tko[8];
#pragma unroll
  for (int j = 0; j < 8; ++j) tko[j] = lltk[q * 8 + j];
  int4* w4 = (int4*)wsB;
#pragma unroll
  for (int nt = 0; nt < 4; ++nt) {
    short8 hi, lo;
#pragma unroll
    for (int j = 0; j < 8; ++j) {
      int o = tko[j];
      float v = (o == -1) ? 1.f
                          : ((o == -2) ? 0.f : lt[o + (wv * 4 + nt) * 18 + col]);
      short h = f2bf(v);
      hi[j] = h;
      lo[j] = f2bf(v - bf2f(h));
    }
    size_t base = ((((size_t)(b * 256 + tile) * 4 + wv) * 4 + nt) * 2);
    w4[(base + 0) * 64 + lane] = __builtin_bit_cast(int4, hi);
    w4[(base + 1) * 64 + lane] = __builtin_bit_cast(int4, lo);
  }
}

// ---------------------------------------------------------------------------
// One diffusion iteration, split-bf16 MFMA logit conv, exp2 epilogue.
// R14: A-fragments held in REGISTERS (8 pairs, 16 coalesced global b128
// from L2-hot wsW, issued before staging) — NO LDS W buffer, no in-loop A
// reads: LDS traffic/block drops ~136 KB -> ~58 KB (the R13-measured
// saturated pipe). (256,4): the only no-spill cap (R12/R13 evidence:
// unified-file need is >84, <=128 regs). LDS = src halo (+depth, FIRST).
// MODE: 0=FIRST (fused depth_latent, z atomic accumulate, unnorm write)
//       1=MID2  (stage src * 1/zsum[halo], write acc * 1/zsum[own])
//       2=MID3  (stage plain — input pre-normalized, write acc * 1/zsum)
//       3=FINAL (stage plain, atomicAdd out += w_td*acc*1/zsum; out=b_td)
// ---------------------------------------------------------------------------
template <int MODE>
__global__ __launch_bounds__(256, 4) void k_diffuse_m(
    const float* __restrict__ depth, const float* __restrict__ src,
    const float* __restrict__ zsum, const float* __restrict__ w_dp,
    const float* __restrict__ b_dp, const short* __restrict__ wsW,
    const short* __restrict__ wsB, float* __restrict__ dst,
    const float* __restrict__ w_td, float* __restrict__ outp) {
  __shared__ float lsrc[CSTR];                     // 2112 B (1 ch halo)
  __shared__ float ldp[(MODE == 0) ? 576 : 4];     // depth halo (FIRST only)

  int b = blockIdx.z / G, g = blockIdx.z % G;      // g = channel
  int x0 = blockIdx.x * 16, y0 = blockIdx.y * 16;
  int tile = blockIdx.y * 16 + blockIdx.x;
  int tid = threadIdx.x, lane = tid & 63, wv = tid >> 6;
  int q = lane >> 4, col = lane & 15;

  // ---- A fragments: 16 coalesced global b128 (L2-hot), issued FIRST so
  // latency hides under the staging phase; held in registers all kernel.
  const short* wA = wsW + (size_t)g * 4096 + lane * 8;
  short8 Ah[4], Al[4];
#pragma unroll
  for (int mt = 0; mt < 4; ++mt) {
    Ah[mt] = *(const short8*)(wA + (mt * 2 + 0) * 512);
    Al[mt] = *(const short8*)(wA + (mt * 2 + 1) * 512);
  }

  if (MODE == 0) {
    for (int idx = tid; idx < 576; idx += 256) {   // depth halo 24x24 @(-4,-4)
      int iy = idx / 24, ix = idx % 24;
      int yy = y0 + iy - 4, xx = x0 + ix - 4;
      bool ok = (yy >= 0 && yy < HH && xx >= 0 && xx < WW);
      ldp[idx] = ok ? depth[(size_t)b * HWSZ + yy * WW + xx] : 0.f;
    }
    __syncthreads();
  }

  // ---- src halo staging (22x22 @(-3,-3)), single channel ----
  for (int idx = tid; idx < 484; idx += 256) {
    int iy = idx / 22, ix = idx % 22;
    int yy = y0 + iy - PADK, xx = x0 + ix - PADK;
    bool ok = (yy >= 0 && yy < HH && xx >= 0 && xx < WW);
    if (MODE == 0) {
      float a = b_dp[g];
#pragma unroll
      for (int dy = 0; dy < 3; ++dy)
#pragma unroll
        for (int dx = 0; dx < 3; ++dx)
          a = fmaf(w_dp[g * 9 + dy * 3 + dx], ldp[(iy + dy) * 24 + (ix + dx)], a);
      lsrc[iy * LSTR + ix] = ok ? a : 0.f;
    } else if (MODE == 1) {
      float sc = 0.f;
      if (ok) sc = 1.f / zsum[b * HWSZ + yy * WW + xx];
      lsrc[iy * LSTR + ix] =
          ok ? src[((size_t)b * CC + g) * HWSZ + yy * WW + xx] * sc : 0.f;
    } else {
      // input already normalized (MID2/MID3 wrote acc * 1/z)
      lsrc[iy * LSTR + ix] =
          ok ? src[((size_t)b * CC + g) * HWSZ + yy * WW + xx] : 0.f;
    }
  }
  __syncthreads();

  // ---- per-lane tap offsets in registers (j = mt*4+i, constant-indexed):
  // t = mt*16 + q*4 + i; off = t + 17*(t/7) - 75, t/7 == (t*37)>>8 (t<=62).
  // Pad taps (t>48) clamp to 48; their e is forced 0 in the mt==3 path.
  int offs[16];
#pragma unroll
  for (int j = 0; j < 16; ++j) {
    int t = (j >> 2) * 16 + q * 4 + (j & 3);
    t = (t < 48) ? t : 48;
    offs[j] = t + 17 * ((t * 37) >> 8) - 75;
  }

  const int4* wB = (const int4*)wsB + ((size_t)(b * 256 + tile) * 4 + wv) * 512;

#pragma unroll 1
  for (int np = 0; np < 2; ++np) {
    // B fragments for this pass's 2 pixel rows (precomputed, coalesced b128)
    short8 Bh0 = __builtin_bit_cast(short8, wB[(np * 4 + 0) * 64 + lane]);
    short8 Bl0 = __builtin_bit_cast(short8, wB[(np * 4 + 1) * 64 + lane]);
    short8 Bh1 = __builtin_bit_cast(short8, wB[(np * 4 + 2) * 64 + lane]);
    short8 Bl1 = __builtin_bit_cast(short8, wB[(np * 4 + 3) * 64 + lane]);
    const float* base = lsrc + (wv * 4 + np * 2 + 3) * LSTR + col + 3;
    float zacc[2] = {0.f, 0.f};
    float accc[2] = {0.f, 0.f};

#pragma unroll
    for (int mt = 0; mt < 4; ++mt) {
      float4v C0 = {0.f, 0.f, 0.f, 0.f}, C1 = {0.f, 0.f, 0.f, 0.f};
      C0 = __builtin_amdgcn_mfma_f32_16x16x32_bf16(Ah[mt], Bh0, C0, 0, 0, 0);
      C1 = __builtin_amdgcn_mfma_f32_16x16x32_bf16(Ah[mt], Bh1, C1, 0, 0, 0);
      C0 = __builtin_amdgcn_mfma_f32_16x16x32_bf16(Ah[mt], Bl0, C0, 0, 0, 0);
      C1 = __builtin_amdgcn_mfma_f32_16x16x32_bf16(Ah[mt], Bl1, C1, 0, 0, 0);
      C0 = __builtin_amdgcn_mfma_f32_16x16x32_bf16(Al[mt], Bh0, C0, 0, 0, 0);
      C1 = __builtin_amdgcn_mfma_f32_16x16x32_bf16(Al[mt], Bh1, C1, 0, 0, 0);

      if (mt < 3) {
        const float* t0 = base + offs[mt * 4 + 0];
        const float* t1 = base + offs[mt * 4 + 1];
        const float* t2 = base + offs[mt * 4 + 2];
        const float* t3 = base + offs[mt * 4 + 3];
        float e00 = __builtin_amdgcn_exp2f(C0[0]);
        float e01 = __builtin_amdgcn_exp2f(C0[1]);
        float e02 = __builtin_amdgcn_exp2f(C0[2]);
        float e03 = __builtin_amdgcn_exp2f(C0[3]);
        float e10 = __builtin_amdgcn_exp2f(C1[0]);
        float e11 = __builtin_amdgcn_exp2f(C1[1]);
        float e12 = __builtin_amdgcn_exp2f(C1[2]);
        float e13 = __builtin_amdgcn_exp2f(C1[3]);
        if (MODE == 0) {
          zacc[0] += (e00 + e01) + (e02 + e03);
          zacc[1] += (e10 + e11) + (e12 + e13);
        }
        float a0 = accc[0], a1 = accc[1];
        a0 = fmaf(e00, t0[0], a0); a1 = fmaf(e10, t0[LSTR], a1);
        a0 = fmaf(e01, t1[0], a0); a1 = fmaf(e11, t1[LSTR], a1);
        a0 = fmaf(e02, t2[0], a0); a1 = fmaf(e12, t2[LSTR], a1);
        a0 = fmaf(e03, t3[0], a0); a1 = fmaf(e13, t3[LSTR], a1);
        accc[0] = a0; accc[1] = a1;
      } else {
        // only tap row 48 (q==0, reg 0) is real in M-tile 3
        const float* t0 = base + offs[12];
        float e0 = (q == 0) ? __builtin_amdgcn_exp2f(C0[0]) : 0.f;
        float e1 = (q == 0) ? __builtin_amdgcn_exp2f(C1[0]) : 0.f;
        if (MODE == 0) { zacc[0] += e0; zacc[1] += e1; }
        accc[0] = fmaf(e0, t0[0], accc[0]);
        accc[1] = fmaf(e1, t0[LSTR], accc[1]);
      }
    }

    // pass complete: reduce across quads, emit
#pragma unroll
    for (int t = 0; t < 2; ++t) {
      float v = accc[t];
      v += __shfl_xor(v, 16, 64);
      v += __shfl_xor(v, 32, 64);
      int p = (y0 + wv * 4 + np * 2 + t) * WW + (x0 + col);
      if (MODE == 0) {
        if (lane < 16) dst[((size_t)b * CC + g) * HWSZ + p] = v;
        float z = zacc[t];
        z += __shfl_xor(z, 16, 64);
        z += __shfl_xor(z, 32, 64);
        if (lane < 16) atomicAdd((float*)&zsum[b * HWSZ + p], z);
      } else if (MODE == 3) {
        if (lane < 16) {
          float rz = 1.f / zsum[b * HWSZ + p];
          atomicAdd(&outp[(size_t)b * HWSZ + p], w_td[g] * v * rz);
        }
      } else {
        // MID2/MID3: write normalized (zsum complete & stable after iter1)
        if (lane < 16) {
          float rz = 1.f / zsum[b * HWSZ + p];
          dst[((size_t)b * CC + g) * HWSZ + p] = v * rz;
        }
      }
    }
  }
}

// ---------------------------------------------------------------------------
extern "C" void kernel_launch(void* const* d_in, const int* in_sizes, int n_in,
                              void* d_out, int out_size, void* d_ws, size_t ws_size,
                              hipStream_t stream) {
  const float* depth = (const float*)d_in[0];
  const float* tex   = (const float*)d_in[1];
  const float* w_dp  = (const float*)d_in[2];
  const float* b_dp  = (const float*)d_in[3];
  const float* w_kp  = (const float*)d_in[4];
  const float* b_kp  = (const float*)d_in[5];
  const float* w_td  = (const float*)d_in[6];
  const float* b_td  = (const float*)d_in[7];
  float* out = (float*)d_out;

  // ws: bufA/bufB (12.58 MB ea) + zsum (0.5 MB) + wsW (0.2 MB) + wsB (16.8 MB)
  char* ws = (char*)d_ws;
  const size_t buf_b = (size_t)BB * CC * HWSZ * 4;
  float* bufA = (float*)ws;
  float* bufB = (float*)(ws + buf_b);
  float* zsum = (float*)(ws + 2 * buf_b);
  short* wsW  = (short*)(ws + 2 * buf_b + (size_t)BB * HWSZ * 4);
  short* wsB  = (short*)(ws + 2 * buf_b + (size_t)BB * HWSZ * 4 + 192 * 512 * 2);

  k_setup<<<dim3(192 + 512 + 512), dim3(256), 0, stream>>>(
      w_kp, b_kp, tex, wsW, wsB, b_td, out, zsum);

  dim3 grid(WW / 16, HH / 16, BB * G), blk(256);

  // iter1 (FIRST): fused depth_latent; unnormalized write + atomic z
  k_diffuse_m<0><<<grid, blk, 0, stream>>>(
      depth, nullptr, zsum, w_dp, b_dp, wsW, wsB, bufB, w_td, nullptr);
  // iter2 (MID2): stage 1/z-folded, write normalized
  k_diffuse_m<1><<<grid, blk, 0, stream>>>(
      depth, bufB, zsum, w_dp, b_dp, wsW, wsB, bufA, w_td, nullptr);
  // iter3 (MID3): stage plain (pre-normalized input), write normalized
  k_diffuse_m<2><<<grid, blk, 0, stream>>>(
      depth, bufA, zsum, w_dp, b_dp, wsW, wsB, bufB, w_td, nullptr);
  // iter4 (FINAL): stage plain, atomic accumulate to out (pre-init b_td)
  k_diffuse_m<3><<<grid, blk, 0, stream>>>(
      depth, bufB, zsum, w_dp, b_dp, wsW, wsB, nullptr, w_td, out);
}

// Round 15
// 255.162 us; speedup vs baseline: 5.5831x; 1.5175x over previous
//
#include <hip/hip_runtime.h>

// Problem constants
#define BB   2
#define HH   256
#define WW   256
#define HWSZ (HH * WW)        // 65536
#define CC   24
#define KSZ  7
#define KK   49               // 7*7
#define PADK 3
#define G    8                // channel groups (3 channels per block — R10 best)
#define CPG  3
#define LSTR 24               // src halo row stride (22 padded to 24)
#define CSTR (22 * LSTR)      // channel stride in lsrc (floats)
#define LOG2E 1.44269504088896340736f

typedef __attribute__((ext_vector_type(8))) short short8;
typedef __attribute__((ext_vector_type(4))) float float4v;

// float -> bf16 bits (round-to-nearest-even) and back
__device__ __forceinline__ short f2bf(float x) {
  unsigned u = __builtin_bit_cast(unsigned, x);
  unsigned r = u + 0x7FFFu + ((u >> 16) & 1u);
  return (short)(r >> 16);
}
__device__ __forceinline__ float bf2f(short h) {
  unsigned u = ((unsigned)(unsigned short)h) << 16;
  return __builtin_bit_cast(float, u);
}

// ---------------------------------------------------------------------------
// Merged setup (one dispatch):
// blocks 0..191: split-bf16 W fragments in FRAG-MAJOR (consumer-lane) order,
//   pre-scaled by log2e. wsW[blk][lane*8+j] = W[m=lane&15][k=(lane>>4)*8+j],
//   blk = ((g*3+c)*4+mt)*2+s.
// blocks 192..703: split-bf16 B fragments (texture patch matrix), identical
//   for all 4 diffusion dispatches.
// blocks 704..1215: init out = b_td and zsum = 0 (FIRST accumulates z
//   atomically; ws is re-poisoned before every timed launch).
// ---------------------------------------------------------------------------
__global__ __launch_bounds__(256) void k_setup(
    const float* __restrict__ w_kp, const float* __restrict__ b_kp,
    const float* __restrict__ tex, short* __restrict__ wsW,
    short* __restrict__ wsB, const float* __restrict__ b_td,
    float* __restrict__ outp, float* __restrict__ zsum) {
  __shared__ float lt[3 * 324];   // 18x18 tex halo
  __shared__ int lltk[32];        // k -> tex-halo offset
  int blk = blockIdx.x;
  if (blk < 192) {
    int s = blk & 1, mt = (blk >> 1) & 3, cg = blk >> 3;   // cg = g*3+c
    for (int idx = threadIdx.x; idx < 512; idx += 256) {
      int l = idx >> 3, j = idx & 7;          // consumer lane, reg element
      int kk = mt * 16 + (l & 15);            // tap row (A row m)
      int k = (l >> 4) * 8 + j;               // K index (q*8+j)
      float v = 0.f;
      if (kk < KK && k < 28)
        v = ((k < 27) ? w_kp[((size_t)cg * KK + kk) * 27 + k]
                      : b_kp[cg * KK + kk]) * LOG2E;
      short hi = f2bf(v);
      short h = (s == 0) ? hi : f2bf(v - bf2f(hi));
      wsW[(size_t)blk * 512 + idx] = h;
    }
    return;
  }
  if (blk >= 704) {
    int i = (blk - 704) * 256 + threadIdx.x;   // 0 .. 131071 = BB*HWSZ
    outp[i] = b_td[0];
    zsum[i] = 0.f;
    return;
  }
  int tb = blk - 192;                     // 0..511
  int b = tb >> 8, tile = tb & 255;
  int y0 = (tile >> 4) * 16, x0 = (tile & 15) * 16;
  int tid = threadIdx.x, lane = tid & 63, wv = tid >> 6;
  int q = lane >> 4, col = lane & 15;

  if (tid < 32) {
    int k = tid, v;
    if (k < 27) v = (k / 9) * 324 + ((k % 9) / 3) * 18 + (k % 3);
    else if (k == 27) v = -1;     // bias slot: patch value 1.0
    else v = -2;                  // K padding: 0.0
    lltk[k] = v;
  }
  for (int idx = tid; idx < 972; idx += 256) {
    int ci = idx / 324, r = idx % 324;
    int iy = r / 18, ix = r % 18;
    int yy = y0 + iy - 1, xx = x0 + ix - 1;
    bool ok = (yy >= 0 && yy < HH && xx >= 0 && xx < WW);
    lt[idx] = ok ? tex[((size_t)b * 3 + ci) * HWSZ + yy * WW + xx] : 0.f;
  }
  __syncthreads();

  int tko[8];
#pragma unroll
  for (int j = 0; j < 8; ++j) tko[j] = lltk[q * 8 + j];
  int4* w4 = (int4*)wsB;
#pragma unroll
  for (int nt = 0; nt < 4; ++nt) {
    short8 hi, lo;
#pragma unroll
    for (int j = 0; j < 8; ++j) {
      int o = tko[j];
      float v = (o == -1) ? 1.f
                          : ((o == -2) ? 0.f : lt[o + (wv * 4 + nt) * 18 + col]);
      short h = f2bf(v);
      hi[j] = h;
      lo[j] = f2bf(v - bf2f(h));
    }
    size_t base = ((((size_t)(b * 256 + tile) * 4 + wv) * 4 + nt) * 2);
    w4[(base + 0) * 64 + lane] = __builtin_bit_cast(int4, hi);
    w4[(base + 1) * 64 + lane] = __builtin_bit_cast(int4, lo);
  }
}

// ---------------------------------------------------------------------------
// One diffusion iteration — R10 inner loop VERBATIM (best measured: np outer
// 2-pass x 2 C-chains, mt unrolled w/ precomputed offs[16], frag-major LDS
// A reads, (256,4) — the only no-spill envelope). Only the epilogue/staging
// differ by MODE (both mechanisms individually validated):
//   MODE 0 FIRST: fused depth_latent staging; write unnormalized; atomic z.
//   MODE 1 MID2 : stage src*(1/zsum[halo]); write v*(1/zsum[own]).
//   MODE 2 MID3 : stage plain (input normalized); write v*(1/zsum[own]).
//   MODE 3 FINAL: stage plain; atomicAdd out += w_td.v*(1/zsum) (out=b_td).
// ---------------------------------------------------------------------------
template <int MODE>
__global__ __launch_bounds__(256, 4) void k_diffuse_m(
    const float* __restrict__ depth, const float* __restrict__ src,
    const float* __restrict__ zsum, const float* __restrict__ w_dp,
    const float* __restrict__ b_dp, const short* __restrict__ wsW,
    const short* __restrict__ wsB, float* __restrict__ dst,
    const float* __restrict__ w_td, float* __restrict__ outp) {
  __shared__ __align__(16) short lw[24 * 512];   // 24576 B (group W frags)
  __shared__ float lsrc[CPG * CSTR];             // 6336 B
  __shared__ float ldp[(MODE == 0) ? 576 : 4];   // depth halo (FIRST only)

  int b = blockIdx.z / G, g = blockIdx.z % G, c0 = g * CPG;
  int x0 = blockIdx.x * 16, y0 = blockIdx.y * 16;
  int tile = blockIdx.y * 16 + blockIdx.x;
  int tid = threadIdx.x, lane = tid & 63, wv = tid >> 6;
  int q = lane >> 4, col = lane & 15;

  // ---- phase A: W->LDS copy (layout-preserving), depth halo ----
  {
    const int4* s4 = (const int4*)(wsW + (size_t)g * 12288);
    int4* d4 = (int4*)lw;
#pragma unroll
    for (int i = 0; i < 6; ++i) d4[tid + i * 256] = s4[tid + i * 256];
  }
  if (MODE == 0) {
    for (int idx = tid; idx < 576; idx += 256) {  // depth halo 24x24 @(-4,-4)
      int iy = idx / 24, ix = idx % 24;
      int yy = y0 + iy - 4, xx = x0 + ix - 4;
      bool ok = (yy >= 0 && yy < HH && xx >= 0 && xx < WW);
      ldp[idx] = ok ? depth[(size_t)b * HWSZ + yy * WW + xx] : 0.f;
    }
  }
  __syncthreads();

  // ---- phase B: src halo staging (22x22 @(-3,-3)) ----
  for (int idx = tid; idx < 484; idx += 256) {
    int iy = idx / 22, ix = idx % 22;
    int yy = y0 + iy - PADK, xx = x0 + ix - PADK;
    bool ok = (yy >= 0 && yy < HH && xx >= 0 && xx < WW);
    if (MODE == 0) {
#pragma unroll
      for (int c = 0; c < CPG; ++c) {
        float a = b_dp[c0 + c];
#pragma unroll
        for (int dy = 0; dy < 3; ++dy)
#pragma unroll
          for (int dx = 0; dx < 3; ++dx)
            a = fmaf(w_dp[(c0 + c) * 9 + dy * 3 + dx],
                     ldp[(iy + dy) * 24 + (ix + dx)], a);
        lsrc[c * CSTR + iy * LSTR + ix] = ok ? a : 0.f;
      }
    } else if (MODE == 1) {
      float sc = 0.f;
      if (ok) sc = 1.f / zsum[b * HWSZ + yy * WW + xx];
#pragma unroll
      for (int c = 0; c < CPG; ++c)
        lsrc[c * CSTR + iy * LSTR + ix] =
            ok ? src[((size_t)b * CC + c0 + c) * HWSZ + yy * WW + xx] * sc : 0.f;
    } else {
      // input already normalized (MID2/MID3 wrote v * 1/z)
#pragma unroll
      for (int c = 0; c < CPG; ++c)
        lsrc[c * CSTR + iy * LSTR + ix] =
            ok ? src[((size_t)b * CC + c0 + c) * HWSZ + yy * WW + xx] : 0.f;
    }
  }
  __syncthreads();

  // ---- per-lane tap offsets in registers (j = mt*4+i, constant-indexed):
  // t = mt*16 + q*4 + i; off = t + 17*(t/7) - 75, t/7 == (t*37)>>8 (t<=62).
  // Pad taps (t>48) clamp to 48; their e is forced 0 in the mt==3 path.
  int offs[16];
#pragma unroll
  for (int j = 0; j < 16; ++j) {
    int t = (j >> 2) * 16 + q * 4 + (j & 3);
    t = (t < 48) ? t : 48;
    offs[j] = t + 17 * ((t * 37) >> 8) - 75;
  }

  const short* lA = lw + lane * 8;   // + ((c*4+mt)*2+s)*512 shorts
  const int4* wB = (const int4*)wsB + ((size_t)(b * 256 + tile) * 4 + wv) * 512;

#pragma unroll 1
  for (int np = 0; np < 2; ++np) {
    // B fragments for this pass's 2 pixel rows (precomputed, coalesced b128)
    short8 Bh0 = __builtin_bit_cast(short8, wB[(np * 4 + 0) * 64 + lane]);
    short8 Bl0 = __builtin_bit_cast(short8, wB[(np * 4 + 1) * 64 + lane]);
    short8 Bh1 = __builtin_bit_cast(short8, wB[(np * 4 + 2) * 64 + lane]);
    short8 Bl1 = __builtin_bit_cast(short8, wB[(np * 4 + 3) * 64 + lane]);
    const float* base = lsrc + (wv * 4 + np * 2 + 3) * LSTR + col + 3;
    int p0g = (y0 + wv * 4 + np * 2 + 0) * WW + (x0 + col);
    int p1g = p0g + WW;
    // 1/z for this pass's two pixels (MODE>=1 consumers)
    float rz0 = 0.f, rz1 = 0.f;
    if (MODE != 0) {
      rz0 = 1.f / zsum[b * HWSZ + p0g];
      rz1 = 1.f / zsum[b * HWSZ + p1g];
    }
    float zacc[2] = {0.f, 0.f}, res[2] = {0.f, 0.f};
    float accc[2] = {0.f, 0.f};

#pragma unroll 1
    for (int c = 0; c < CPG; ++c) {
      const short* lAc = lA + c * 2048;   // c*4 frags * 512 shorts
#pragma unroll
      for (int mt = 0; mt < 4; ++mt) {
        short8 Ah = *(const short8*)(lAc + mt * 1024);
        short8 Al = *(const short8*)(lAc + mt * 1024 + 512);

        float4v C0 = {0.f, 0.f, 0.f, 0.f}, C1 = {0.f, 0.f, 0.f, 0.f};
        C0 = __builtin_amdgcn_mfma_f32_16x16x32_bf16(Ah, Bh0, C0, 0, 0, 0);
        C1 = __builtin_amdgcn_mfma_f32_16x16x32_bf16(Ah, Bh1, C1, 0, 0, 0);
        C0 = __builtin_amdgcn_mfma_f32_16x16x32_bf16(Ah, Bl0, C0, 0, 0, 0);
        C1 = __builtin_amdgcn_mfma_f32_16x16x32_bf16(Ah, Bl1, C1, 0, 0, 0);
        C0 = __builtin_amdgcn_mfma_f32_16x16x32_bf16(Al, Bh0, C0, 0, 0, 0);
        C1 = __builtin_amdgcn_mfma_f32_16x16x32_bf16(Al, Bh1, C1, 0, 0, 0);

        if (mt < 3) {
          const float* t0 = base + offs[mt * 4 + 0];
          const float* t1 = base + offs[mt * 4 + 1];
          const float* t2 = base + offs[mt * 4 + 2];
          const float* t3 = base + offs[mt * 4 + 3];
          float e00 = __builtin_amdgcn_exp2f(C0[0]);
          float e01 = __builtin_amdgcn_exp2f(C0[1]);
          float e02 = __builtin_amdgcn_exp2f(C0[2]);
          float e03 = __builtin_amdgcn_exp2f(C0[3]);
          float e10 = __builtin_amdgcn_exp2f(C1[0]);
          float e11 = __builtin_amdgcn_exp2f(C1[1]);
          float e12 = __builtin_amdgcn_exp2f(C1[2]);
          float e13 = __builtin_amdgcn_exp2f(C1[3]);
          if (MODE == 0) {
            zacc[0] += (e00 + e01) + (e02 + e03);
            zacc[1] += (e10 + e11) + (e12 + e13);
          }
          float a0 = accc[0], a1 = accc[1];
          a0 = fmaf(e00, t0[0], a0); a1 = fmaf(e10, t0[LSTR], a1);
          a0 = fmaf(e01, t1[0], a0); a1 = fmaf(e11, t1[LSTR], a1);
          a0 = fmaf(e02, t2[0], a0); a1 = fmaf(e12, t2[LSTR], a1);
          a0 = fmaf(e03, t3[0], a0); a1 = fmaf(e13, t3[LSTR], a1);
          accc[0] = a0; accc[1] = a1;
        } else {
          // only tap row 48 (q==0, reg 0) is real in M-tile 3
          const float* t0 = base + offs[12];
          float e0 = (q == 0) ? __builtin_amdgcn_exp2f(C0[0]) : 0.f;
          float e1 = (q == 0) ? __builtin_amdgcn_exp2f(C1[0]) : 0.f;
          if (MODE == 0) { zacc[0] += e0; zacc[1] += e1; }
          accc[0] = fmaf(e0, t0[0], accc[0]);
          accc[1] = fmaf(e1, t0[LSTR], accc[1]);
        }
      }
      // channel c complete: reduce across quads, emit
#pragma unroll
      for (int t = 0; t < 2; ++t) {
        float v = accc[t];
        v += __shfl_xor(v, 16, 64);
        v += __shfl_xor(v, 32, 64);
        int p = (t == 0) ? p0g : p1g;
        float rz = (t == 0) ? rz0 : rz1;
        if (MODE == 3) {
          res[t] = fmaf(w_td[c0 + c], v, res[t]);
        } else if (MODE == 0) {
          if (lane < 16) dst[((size_t)b * CC + c0 + c) * HWSZ + p] = v;
        } else {
          if (lane < 16) dst[((size_t)b * CC + c0 + c) * HWSZ + p] = v * rz;
        }
        accc[t] = 0.f;
      }
      base += CSTR;
    }
    // pass tail: z (FIRST, atomic) / fused to_depth accumulate (FINAL)
#pragma unroll
    for (int t = 0; t < 2; ++t) {
      int p = (t == 0) ? p0g : p1g;
      if (MODE == 0) {
        float z = zacc[t];
        z += __shfl_xor(z, 16, 64);
        z += __shfl_xor(z, 32, 64);
        if (lane < 16) atomicAdd((float*)&zsum[b * HWSZ + p], z);
      }
      if (MODE == 3) {
        float rz = (t == 0) ? rz0 : rz1;
        if (lane < 16) atomicAdd(&outp[(size_t)b * HWSZ + p], res[t] * rz);
      }
    }
  }
}

// ---------------------------------------------------------------------------
extern "C" void kernel_launch(void* const* d_in, const int* in_sizes, int n_in,
                              void* d_out, int out_size, void* d_ws, size_t ws_size,
                              hipStream_t stream) {
  const float* depth = (const float*)d_in[0];
  const float* tex   = (const float*)d_in[1];
  const float* w_dp  = (const float*)d_in[2];
  const float* b_dp  = (const float*)d_in[3];
  const float* w_kp  = (const float*)d_in[4];
  const float* b_kp  = (const float*)d_in[5];
  const float* w_td  = (const float*)d_in[6];
  const float* b_td  = (const float*)d_in[7];
  float* out = (float*)d_out;

  // ws: bufA/bufB (12.58 MB ea) + zsum (0.5 MB) + wsW (0.2 MB) + wsB (16.8 MB)
  char* ws = (char*)d_ws;
  const size_t buf_b = (size_t)BB * CC * HWSZ * 4;
  float* bufA = (float*)ws;
  float* bufB = (float*)(ws + buf_b);
  float* zsum = (float*)(ws + 2 * buf_b);
  short* wsW  = (short*)(ws + 2 * buf_b + (size_t)BB * HWSZ * 4);
  short* wsB  = (short*)(ws + 2 * buf_b + (size_t)BB * HWSZ * 4 + 192 * 512 * 2);

  k_setup<<<dim3(192 + 512 + 512), dim3(256), 0, stream>>>(
      w_kp, b_kp, tex, wsW, wsB, b_td, out, zsum);

  dim3 grid(WW / 16, HH / 16, BB * G), blk(256);

  // iter1 (FIRST): fused depth_latent; unnormalized write + atomic z
  k_diffuse_m<0><<<grid, blk, 0, stream>>>(
      depth, nullptr, zsum, w_dp, b_dp, wsW, wsB, bufB, w_td, nullptr);
  // iter2 (MID2): stage 1/z-folded, write normalized
  k_diffuse_m<1><<<grid, blk, 0, stream>>>(
      depth, bufB, zsum, w_dp, b_dp, wsW, wsB, bufA, w_td, nullptr);
  // iter3 (MID3): stage plain (pre-normalized input), write normalized
  k_diffuse_m<2><<<grid, blk, 0, stream>>>(
      depth, bufA, zsum, w_dp, b_dp, wsW, wsB, bufB, w_td, nullptr);
  // iter4 (FINAL): stage plain, atomic accumulate to out (pre-init b_td)
  k_diffuse_m<3><<<grid, blk, 0, stream>>>(
      depth, bufB, zsum, w_dp, b_dp, wsW, wsB, nullptr, w_td, out);
}